// Round 2
// baseline (440.654 us; speedup 1.0000x reference)
//
#include <hip/hip_runtime.h>

// EvoBinarizedLayer: out[p,b,o] = x@W0 + (1-x)@W1  =  x@(W0-W1) + colsum_i(W1)
// x:[32,512,1024] {0,1} fp32; w:[2,32,1024,1024] {0,1} fp32; out fp32.
// Memory-bound (384 MB min traffic, ~61us floor @6.3TB/s). bf16 MFMA, exact.
//
// R2: w-once-by-construction. BM=512 (all of B), BN=128 -> each (p,o-block)
// w panel is read by exactly ONE block: w's 256 MB fetched once from HBM with
// no reliance on inter-block L2 hits (R1 evidence: L2 was only partially
// absorbing the 2x w re-read; kernel ~110us vs 61us floor). w loads are
// non-temporal (single-use stream, keep L2 for x). x panels (2 MB per p) are
// shared 8-way by the o-blocks of the same p, co-located on one XCD by the
// swizzle: per-iter per-XCD x footprint 256 KB << 4 MB L2.

namespace {

constexpr int PP = 32;
constexpr int BB = 512;
constexpr int II = 1024;
constexpr int OO = 1024;

constexpr int BM = 512;   // b tile = whole B
constexpr int BN = 128;   // o tile
constexpr int BK = 32;    // k tile (= one 16x16x32 MFMA K)

constexpr int KPA = 40;   // A LDS row stride in bf16 elems (80B, 16B-aligned)

// B LDS addressing (bf16 elems): [o][k] with 16B pad every 4 rows.
// Keeps ds_read_b128 16B-aligned; spreads transpose-write banks ~8-way.
__device__ __forceinline__ int boff(int o, int k) {
    return o * 40 + (o >> 2) * 8 + k;
}

typedef __attribute__((ext_vector_type(8))) short bf16x8;
typedef __attribute__((ext_vector_type(4))) float f32x4;
typedef __attribute__((ext_vector_type(2))) float f32x2;

constexpr int A_BYTES = BM * KPA * 2;                 // 40960
constexpr int B_BYTES = (BN * 40 + (BN / 4) * 8) * 2; // 10752
constexpr int SMEM_BYTES = A_BYTES + B_BYTES;         // 51712 < 64KB

// fp32 -> bf16 by truncation: exact for {0,+-1}. Pack two into one u32 (lo=first).
__device__ __forceinline__ unsigned pk2(float lo, float hi) {
    return (__float_as_uint(lo) >> 16) | (__float_as_uint(hi) & 0xFFFF0000u);
}

__global__ __launch_bounds__(1024) void ebl_kernel(const float* __restrict__ x,
                                                   const float* __restrict__ w,
                                                   float* __restrict__ out) {
    __shared__ __align__(16) char smem[SMEM_BYTES];
    unsigned short* As = (unsigned short*)smem;            // [BM][KPA] bf16, [b][k]
    unsigned short* Bs = (unsigned short*)(smem + A_BYTES);// boff-layout bf16, [o][k]
    float* Scr    = (float*)smem;           // reused after k-loop: 16 waves x 128 o
    float* ColSum = (float*)(smem + 8192);  // 128 floats (still inside A region)

    const int t  = (int)threadIdx.x;
    const int l  = t & 63;
    const int wv = t >> 6;       // wave 0..15
    const int wm = wv & 3;       // wave m (b) tile: rows wm*128..+127
    const int wn = wv >> 2;      // wave n (o) tile: cols wn*32..+31
    const int lq = l >> 4;       // quad
    const int ln = l & 15;

    // XCD-aware swizzle: XCD k (= bid%8, round-robin dispatch) gets the
    // contiguous work chunk [32k, 32k+32): 4 p-slices x all 8 o-blocks,
    // so the 8-way x sharing is same-XCD.
    const int bid = (int)blockIdx.x;
    const int wid = (bid & 7) * 32 + (bid >> 3);
    const int p   = wid >> 3;          // 0..31, 4 per XCD chunk
    const int o0  = (wid & 7) * BN;    // o-block

    const float* xp  = x + (size_t)p * BB * II;
    const float* w0p = w + (size_t)p * II * OO;
    const float* w1p = w + (size_t)(PP + p) * II * OO;

    // A staging: 4 loads/thread: rows a_row+128j; 8 lanes cover a 32-float row seg.
    const int a_row = t >> 3;            // 0..127
    const int a_col = (t & 7) * 4;
    // B staging: wave wv loads w k-rows 2wv, 2wv+1; lane l covers o = 2l, 2l+1.
    const int oc = 2 * l;

    // Fragment LDS read offsets are k-loop invariant.
    int a_rd[8], b_rd[2];
#pragma unroll
    for (int mt = 0; mt < 8; ++mt)
        a_rd[mt] = (wm * 128 + mt * 16 + ln) * KPA + lq * 8;
#pragma unroll
    for (int nt = 0; nt < 2; ++nt)
        b_rd[nt] = boff(wn * 32 + nt * 16 + ln, lq * 8);

    f32x4 acc[8][2];
#pragma unroll
    for (int mt = 0; mt < 8; ++mt)
#pragma unroll
        for (int nt = 0; nt < 2; ++nt)
            acc[mt][nt] = (f32x4){0.f, 0.f, 0.f, 0.f};

    f32x2 csum = (f32x2){0.f, 0.f};  // colsum(W1) partial, o = oc..oc+1, k = 2wv,2wv+1

    const float* xa0  = xp + (size_t)a_row * II + a_col;
    const float* xa1  = xa0 + (size_t)128 * II;
    const float* xa2  = xa0 + (size_t)256 * II;
    const float* xa3  = xa0 + (size_t)384 * II;
    const float* wb00 = w0p + (size_t)(2 * wv) * OO + o0 + oc;
    const float* wb01 = w0p + (size_t)(2 * wv + 1) * OO + o0 + oc;
    const float* wb10 = w1p + (size_t)(2 * wv) * OO + o0 + oc;
    const float* wb11 = w1p + (size_t)(2 * wv + 1) * OO + o0 + oc;

    for (int kk = 0; kk < II; kk += BK) {
        // ---- global loads (fp32, coalesced). w stream is non-temporal ----
        f32x4 a0 = *(const f32x4*)(xa0 + kk);
        f32x4 a1 = *(const f32x4*)(xa1 + kk);
        f32x4 a2 = *(const f32x4*)(xa2 + kk);
        f32x4 a3 = *(const f32x4*)(xa3 + kk);
        f32x2 q00 = __builtin_nontemporal_load((const f32x2*)(wb00 + (size_t)kk * OO));
        f32x2 q01 = __builtin_nontemporal_load((const f32x2*)(wb01 + (size_t)kk * OO));
        f32x2 q10 = __builtin_nontemporal_load((const f32x2*)(wb10 + (size_t)kk * OO));
        f32x2 q11 = __builtin_nontemporal_load((const f32x2*)(wb11 + (size_t)kk * OO));

        __syncthreads();  // prior iteration's LDS reads complete

        // ---- A: truncate-convert to bf16, k-contiguous b64 writes ----
        *(uint2*)(&As[a_row * KPA + a_col]) =
            make_uint2(pk2(a0.x, a0.y), pk2(a0.z, a0.w));
        *(uint2*)(&As[(a_row + 128) * KPA + a_col]) =
            make_uint2(pk2(a1.x, a1.y), pk2(a1.z, a1.w));
        *(uint2*)(&As[(a_row + 256) * KPA + a_col]) =
            make_uint2(pk2(a2.x, a2.y), pk2(a2.z, a2.w));
        *(uint2*)(&As[(a_row + 384) * KPA + a_col]) =
            make_uint2(pk2(a3.x, a3.y), pk2(a3.z, a3.w));

        // ---- B: diff = W0-W1 (in {-1,0,1}), colsum(W1), register transpose ----
        f32x2 d0 = q00 - q10;   // k = 2wv
        f32x2 d1 = q01 - q11;   // k = 2wv+1
        csum += q10;
        csum += q11;
        const int kloc = 2 * wv;
#pragma unroll
        for (int c = 0; c < 2; ++c)
            *(unsigned*)(&Bs[boff(oc + c, kloc)]) = pk2(d0[c], d1[c]);

        __syncthreads();

        // ---- MFMA: wave tile 128x32, one K=32 step ----
        bf16x8 bfm[2];
#pragma unroll
        for (int nt = 0; nt < 2; ++nt)
            bfm[nt] = *(const bf16x8*)(&Bs[b_rd[nt]]);
#pragma unroll
        for (int mt = 0; mt < 8; ++mt) {
            bf16x8 af = *(const bf16x8*)(&As[a_rd[mt]]);
#pragma unroll
            for (int nt = 0; nt < 2; ++nt)
                acc[mt][nt] = __builtin_amdgcn_mfma_f32_16x16x32_bf16(
                    af, bfm[nt], acc[mt][nt], 0, 0, 0);
        }
    }

    // ---- colsum(W1) reduction: 16 per-wave k-pair partials -> 128 column sums ----
    __syncthreads();                       // last MFMA reads done; reuse A region
    *(f32x2*)(&Scr[wv * 128 + oc]) = csum;
    __syncthreads();
    if (t < 128) {
        float s = 0.f;
#pragma unroll
        for (int q = 0; q < 16; ++q) s += Scr[q * 128 + t];
        ColSum[t] = s;
    }
    __syncthreads();

    // ---- epilogue: C/D layout col=lane&15, row=quad*4+reg (m89/m91-verified) ----
    float* op = out + (size_t)p * BB * OO + o0;
#pragma unroll
    for (int nt = 0; nt < 2; ++nt) {
        const int ocol = wn * 32 + nt * 16 + ln;
        const float cs = ColSum[ocol];
#pragma unroll
        for (int mt = 0; mt < 8; ++mt) {
            const int row = wm * 128 + mt * 16 + lq * 4;
#pragma unroll
            for (int r = 0; r < 4; ++r)
                op[(size_t)(row + r) * OO + ocol] = acc[mt][nt][r] + cs;
        }
    }
}

}  // namespace

extern "C" void kernel_launch(void* const* d_in, const int* in_sizes, int n_in,
                              void* d_out, int out_size, void* d_ws, size_t ws_size,
                              hipStream_t stream) {
    const float* x = (const float*)d_in[0];
    const float* w = (const float*)d_in[1];
    float* out = (float*)d_out;
    dim3 grid(PP * (OO / BN), 1, 1);  // 256 blocks, 1/CU
    ebl_kernel<<<grid, dim3(1024, 1, 1), 0, stream>>>(x, w, out);
}

// Round 3
// 432.280 us; speedup vs baseline: 1.0194x; 1.0194x over previous
//
#include <hip/hip_runtime.h>

// EvoBinarizedLayer: out[p,b,o] = x@W0 + (1-x)@W1  =  x@(W0-W1) + colsum_i(W1)
// x:[32,512,1024] {0,1} fp32; w:[2,32,1024,1024] {0,1} fp32; out fp32.
// Memory-bound (384 MB min traffic). bf16 MFMA, exact.
//
// R3: 2 blocks/CU for continuous load issue. R1 vs R2 showed structural
// traffic changes are neutral -> kernel is issue-bound: a single 1024-thread
// block's 16 waves all drain at the same __syncthreads each k-iter, so no
// global loads are in flight during LDS-write+MFMA+barrier. Fix via TLP:
// 512 blocks x 512 threads (BM=256, BN=128), 2 independent barrier groups
// per CU overlap each other's load phases (m114 mechanism). Per-CU per-iter
// bytes and MFMA work unchanged.

namespace {

constexpr int PP = 32;
constexpr int BB = 512;
constexpr int II = 1024;
constexpr int OO = 1024;

constexpr int BM = 256;   // b tile
constexpr int BN = 128;   // o tile
constexpr int BK = 32;    // k tile (= one 16x16x32 MFMA K)

constexpr int KPA = 40;   // A LDS row stride in bf16 elems (80B, 16B-aligned)

// B LDS addressing (bf16 elems): [o][k] with 16B pad every 4 rows.
__device__ __forceinline__ int boff(int o, int k) {
    return o * 40 + (o >> 2) * 8 + k;
}

typedef __attribute__((ext_vector_type(8))) short bf16x8;
typedef __attribute__((ext_vector_type(4))) float f32x4;

constexpr int A_BYTES = BM * KPA * 2;                 // 20480
constexpr int B_BYTES = (BN * 40 + (BN / 4) * 8) * 2; // 10752
constexpr int SMEM_BYTES = A_BYTES + B_BYTES;         // 31232 -> 2 blocks = 62.5KB/CU

// fp32 -> bf16 by truncation: exact for {0,+-1}. Pack two into one u32 (lo=first).
__device__ __forceinline__ unsigned pk2(float lo, float hi) {
    return (__float_as_uint(lo) >> 16) | (__float_as_uint(hi) & 0xFFFF0000u);
}

__global__ __launch_bounds__(512, 4) void ebl_kernel(const float* __restrict__ x,
                                                     const float* __restrict__ w,
                                                     float* __restrict__ out) {
    __shared__ __align__(16) char smem[SMEM_BYTES];
    unsigned short* As = (unsigned short*)smem;            // [BM][KPA] bf16, [b][k]
    unsigned short* Bs = (unsigned short*)(smem + A_BYTES);// boff-layout bf16, [o][k]
    float* Scr    = (float*)smem;           // reused after k-loop: 16 x 128 partials
    float* ColSum = (float*)(smem + 8192);  // 128 floats (still inside A region)

    const int t  = (int)threadIdx.x;     // 0..511
    const int l  = t & 63;
    const int wv = t >> 6;       // wave 0..7
    const int wm = wv & 3;       // wave m (b) tile: rows wm*64..+63
    const int wn = wv >> 2;      // wave n (o) tile: cols wn*64..+63
    const int lq = l >> 4;       // quad
    const int ln = l & 15;

    // XCD-aware swizzle: 512 blocks = 8 XCDs x 64. XCD k (= bid%8) gets works
    // [64k, 64k+64) = 4 p-slices x (8 o-blocks x 2 b-blocks). w panel shared by
    // the 2 adjacent-b works; x panel shared by all 16 works of a p: same XCD.
    const int bid = (int)blockIdx.x;
    const int wid = (bid & 7) * 64 + (bid >> 3);
    const int p   = wid >> 4;              // 0..31, 4 per XCD chunk
    const int rem = wid & 15;
    const int b0  = (rem & 1) * BM;        // 2 b-blocks
    const int o0  = (rem >> 1) * BN;       // 8 o-blocks

    const float* xp  = x + ((size_t)p * BB + b0) * II;
    const float* w0p = w + (size_t)p * II * OO;
    const float* w1p = w + (size_t)(PP + p) * II * OO;

    // A staging: 4 loads/thread: rows a_row+64j; 8 lanes cover a 32-float row seg.
    const int a_row = t >> 3;            // 0..63
    const int a_col = (t & 7) * 4;
    // B staging: thread covers k rows bk0, bk0+1 at o-group og..og+3 (both tensors).
    const int bk0 = 2 * (t >> 5);        // 0,2,..,30 (even)
    const int og  = (t & 31) * 4;        // 0..124

    // Fragment LDS read offsets are k-loop invariant.
    int a_rd[4], b_rd[4];
#pragma unroll
    for (int mt = 0; mt < 4; ++mt)
        a_rd[mt] = (wm * 64 + mt * 16 + ln) * KPA + lq * 8;
#pragma unroll
    for (int nt = 0; nt < 4; ++nt)
        b_rd[nt] = boff(wn * 64 + nt * 16 + ln, lq * 8);

    f32x4 acc[4][4];
#pragma unroll
    for (int mt = 0; mt < 4; ++mt)
#pragma unroll
        for (int nt = 0; nt < 4; ++nt)
            acc[mt][nt] = (f32x4){0.f, 0.f, 0.f, 0.f};

    f32x4 csum = (f32x4){0.f, 0.f, 0.f, 0.f};  // colsum(W1) partial, o = og..og+3

    const float* xa0  = xp + (size_t)a_row * II + a_col;
    const float* xa1  = xa0 + (size_t)64 * II;
    const float* xa2  = xa0 + (size_t)128 * II;
    const float* xa3  = xa0 + (size_t)192 * II;
    const float* wb00 = w0p + (size_t)bk0 * OO + o0 + og;        // W0 row bk0
    const float* wb01 = wb00 + OO;                               // W0 row bk0+1
    const float* wb10 = w1p + (size_t)bk0 * OO + o0 + og;        // W1 row bk0
    const float* wb11 = wb10 + OO;                               // W1 row bk0+1

    for (int kk = 0; kk < II; kk += BK) {
        // ---- global loads (fp32, dwordx4, fully coalesced) ----
        f32x4 a0  = *(const f32x4*)(xa0 + kk);
        f32x4 a1  = *(const f32x4*)(xa1 + kk);
        f32x4 a2  = *(const f32x4*)(xa2 + kk);
        f32x4 a3  = *(const f32x4*)(xa3 + kk);
        f32x4 q00 = *(const f32x4*)(wb00 + (size_t)kk * OO);
        f32x4 q01 = *(const f32x4*)(wb01 + (size_t)kk * OO);
        f32x4 q10 = *(const f32x4*)(wb10 + (size_t)kk * OO);
        f32x4 q11 = *(const f32x4*)(wb11 + (size_t)kk * OO);

        __syncthreads();  // prior iteration's LDS reads complete

        // ---- A: truncate-convert to bf16, k-contiguous b64 writes ----
        *(uint2*)(&As[a_row * KPA + a_col]) =
            make_uint2(pk2(a0.x, a0.y), pk2(a0.z, a0.w));
        *(uint2*)(&As[(a_row + 64) * KPA + a_col]) =
            make_uint2(pk2(a1.x, a1.y), pk2(a1.z, a1.w));
        *(uint2*)(&As[(a_row + 128) * KPA + a_col]) =
            make_uint2(pk2(a2.x, a2.y), pk2(a2.z, a2.w));
        *(uint2*)(&As[(a_row + 192) * KPA + a_col]) =
            make_uint2(pk2(a3.x, a3.y), pk2(a3.z, a3.w));

        // ---- B: diff = W0-W1 (in {-1,0,1}), colsum(W1), register transpose ----
        f32x4 d0 = q00 - q10;   // k = bk0
        f32x4 d1 = q01 - q11;   // k = bk0+1
        csum += q10;
        csum += q11;
#pragma unroll
        for (int c = 0; c < 4; ++c)
            *(unsigned*)(&Bs[boff(og + c, bk0)]) = pk2(d0[c], d1[c]);

        __syncthreads();

        // ---- MFMA: wave tile 64x64, one K=32 step ----
        bf16x8 af[4], bfm[4];
#pragma unroll
        for (int mt = 0; mt < 4; ++mt)
            af[mt] = *(const bf16x8*)(&As[a_rd[mt]]);
#pragma unroll
        for (int nt = 0; nt < 4; ++nt)
            bfm[nt] = *(const bf16x8*)(&Bs[b_rd[nt]]);
#pragma unroll
        for (int mt = 0; mt < 4; ++mt)
#pragma unroll
            for (int nt = 0; nt < 4; ++nt)
                acc[mt][nt] = __builtin_amdgcn_mfma_f32_16x16x32_bf16(
                    af[mt], bfm[nt], acc[mt][nt], 0, 0, 0);
    }

    // ---- colsum(W1) reduction: 16 k-group partials -> 128 column sums ----
    __syncthreads();                       // last MFMA reads done; reuse A region
    *(f32x4*)(&Scr[(t >> 5) * 128 + og]) = csum;
    __syncthreads();
    if (t < 128) {
        float s = 0.f;
#pragma unroll
        for (int q = 0; q < 16; ++q) s += Scr[q * 128 + t];
        ColSum[t] = s;
    }
    __syncthreads();

    // ---- epilogue: C/D layout col=lane&15, row=quad*4+reg (m89/m91-verified) ----
    float* op = out + (size_t)p * BB * OO + o0;
#pragma unroll
    for (int nt = 0; nt < 4; ++nt) {
        const int ocol = wn * 64 + nt * 16 + ln;
        const float cs = ColSum[ocol];
#pragma unroll
        for (int mt = 0; mt < 4; ++mt) {
            const int row = b0 + wm * 64 + mt * 16 + lq * 4;
#pragma unroll
            for (int r = 0; r < 4; ++r)
                op[(size_t)(row + r) * OO + ocol] = acc[mt][nt][r] + cs;
        }
    }
}

}  // namespace

extern "C" void kernel_launch(void* const* d_in, const int* in_sizes, int n_in,
                              void* d_out, int out_size, void* d_ws, size_t ws_size,
                              hipStream_t stream) {
    const float* x = (const float*)d_in[0];
    const float* w = (const float*)d_in[1];
    float* out = (float*)d_out;
    dim3 grid(PP * (BB / BM) * (OO / BN), 1, 1);  // 512 blocks = 2/CU
    ebl_kernel<<<grid, dim3(512, 1, 1), 0, stream>>>(x, w, out);
}